// Round 7
// baseline (117.703 us; speedup 1.0000x reference)
//
#include <hip/hip_runtime.h>
#include <hip/hip_bf16.h>

#define B_ 32
#define N_ 128
#define D_ 512
#define A_ 512
#define R_ (B_*N_)     // 4096 rows
#define OC 1024        // fused Y cols (E1 | E2)
#define CEXP 2.8853900817779268f   // 2*log2(e)

typedef __attribute__((ext_vector_type(8))) short  frag_ab;   // 8 bf16
typedef __attribute__((ext_vector_type(4))) float  frag_cd;   // 4 f32

__device__ inline unsigned pack2bf(float a, float b) {
    unsigned ua = __builtin_bit_cast(unsigned, a) + 0x8000u;
    unsigned ub = __builtin_bit_cast(unsigned, b) + 0x8000u;
    return __builtin_amdgcn_perm(ub, ua, 0x07060302);
}
__device__ inline float bf2f_lo(unsigned u){ return __builtin_bit_cast(float, u << 16); }
__device__ inline float bf2f_hi(unsigned u){ return __builtin_bit_cast(float, u & 0xffff0000u); }

// ---------------- Kernel 0: fp32 -> bf16 conversion of X, W1, W2 ----------
__global__ __launch_bounds__(256) void k0_cvt(
    const float* __restrict__ X, const float* __restrict__ W1,
    const float* __restrict__ W2,
    unsigned short* __restrict__ Xb, unsigned short* __restrict__ W1b,
    unsigned short* __restrict__ W2b)
{
    const int NX = R_*D_/8, NW = A_*D_/8;
    int i = blockIdx.x*256 + threadIdx.x;
    const float* src; unsigned short* dst; int off;
    if (i < NX)            { src = X;  dst = Xb;  off = i; }
    else if (i < NX+NW)    { src = W1; dst = W1b; off = i-NX; }
    else if (i < NX+2*NW)  { src = W2; dst = W2b; off = i-NX-NW; }
    else return;
    float4 a = ((const float4*)src)[off*2];
    float4 c = ((const float4*)src)[off*2+1];
    uint4 o;
    o.x = pack2bf(a.x,a.y); o.y = pack2bf(a.z,a.w);
    o.z = pack2bf(c.x,c.y); o.w = pack2bf(c.z,c.w);
    ((uint4*)dst)[off] = o;
}

// ---------------- Kernel 1: Yb = bf16(exp2(C*(X*[W1;W2]^T + [b1;b2]))) ----
// 64x64 tile, BK=64, 4 waves (2x2, 32x32 each), LDS dbuf, write-late staging.
#define BK1 64
#define LDK 68    // +4 bf16 pad

__global__ __launch_bounds__(256) void k1_mfma(
    const unsigned short* __restrict__ Xb,
    const unsigned short* __restrict__ W1b, const float* __restrict__ b1,
    const unsigned short* __restrict__ W2b, const float* __restrict__ b2,
    unsigned short* __restrict__ Yb)
{
    __shared__ unsigned short As[2][64*LDK];
    __shared__ unsigned short Bs[2][64*LDK];

    const int t = threadIdx.x, lane = t&63, wid = t>>6;
    const int wr = wid>>1, wc = wid&1;
    const int row0 = blockIdx.x*64, col0 = blockIdx.y*64;
    const unsigned short* Wb = (col0 < A_) ? W1b : W2b;
    const float* bb = (col0 < A_) ? b1 : b2;
    const int wrow0 = col0 & (A_-1);

    const int srow = t>>3;        // 0..31 (staging row, q adds 32)
    const int scol = (t&7)*8;     // 0..56 elems

    frag_cd acc[2][2];
#pragma unroll
    for (int i=0;i<2;++i)
#pragma unroll
        for (int j=0;j<2;++j) acc[i][j] = frag_cd{0.f,0.f,0.f,0.f};

    const int fr = lane&15, g8 = (lane>>4)*8;

    uint4 ra[2], rb[2];
#pragma unroll
    for (int q=0;q<2;++q){
        int r = q*32 + srow;
        ra[q] = *(const uint4*)&Xb[(size_t)(row0 +r)*D_ + scol];
        rb[q] = *(const uint4*)&Wb[(size_t)(wrow0+r)*D_ + scol];
    }
#pragma unroll
    for (int q=0;q<2;++q){
        int r = q*32 + srow;
        *(uint4*)&As[0][r*LDK + scol] = ra[q];
        *(uint4*)&Bs[0][r*LDK + scol] = rb[q];
    }
    __syncthreads();

#pragma unroll
    for (int s=0; s<8; ++s) {
        const int cur = s&1;
        if (s<7) {                 // early-issue next K-chunk's loads
            const int k0 = (s+1)*BK1;
#pragma unroll
            for (int q=0;q<2;++q){
                int r = q*32 + srow;
                ra[q] = *(const uint4*)&Xb[(size_t)(row0 +r)*D_ + k0 + scol];
                rb[q] = *(const uint4*)&Wb[(size_t)(wrow0+r)*D_ + k0 + scol];
            }
        }
        frag_ab af[2][2], bf[2][2];
#pragma unroll
        for (int fi=0;fi<2;++fi)
#pragma unroll
            for (int ks=0;ks<2;++ks) {
                af[fi][ks] = *(const frag_ab*)&As[cur][(wr*32+fi*16+fr)*LDK + ks*32 + g8];
                bf[fi][ks] = *(const frag_ab*)&Bs[cur][(wc*32+fi*16+fr)*LDK + ks*32 + g8];
            }
#pragma unroll
        for (int ks=0;ks<2;++ks)
#pragma unroll
            for (int fi=0;fi<2;++fi)
#pragma unroll
                for (int fj=0;fj<2;++fj)
                    acc[fi][fj] = __builtin_amdgcn_mfma_f32_16x16x32_bf16(
                        af[fi][ks], bf[fj][ks], acc[fi][fj], 0, 0, 0);
        if (s<7) {                 // write-late into the other buffer
#pragma unroll
            for (int q=0;q<2;++q){
                int r = q*32 + srow;
                *(uint4*)&As[cur^1][r*LDK + scol] = ra[q];
                *(uint4*)&Bs[cur^1][r*LDK + scol] = rb[q];
            }
        }
        __syncthreads();
    }

    // epilogue: C/D layout col=lane&15, row=(lane>>4)*4+r; store bf16(exp2)
#pragma unroll
    for (int fi=0;fi<2;++fi){
        const int rr = row0 + wr*32 + fi*16 + (lane>>4)*4;
#pragma unroll
        for (int fj=0;fj<2;++fj){
            const int cc = col0 + wc*32 + fj*16 + (lane&15);
            const float bias = bb[cc & (A_-1)];
#pragma unroll
            for (int r=0;r<4;++r){
                float e = __builtin_amdgcn_exp2f(CEXP*(acc[fi][fj][r] + bias));
                Yb[(size_t)(rr+r)*OC + cc] =
                    (unsigned short)((__builtin_bit_cast(unsigned, e) + 0x8000u) >> 16);
            }
        }
    }
}

// ---------------- Kernel 2 ----------------
// out[b,i,j] = wsum - 2*sum_a wo[a]/(1 + E1[j,a]*E2[i+1,a]) + bout
// 32j x 32i block tile, 2x2 per thread (5B LDS/tanh), ACH=128, LDS dbuf,
// write-late single barrier per chunk. Grid 512 = 2 blk/CU.
#define ACH 128
#define LDA2 (ACH+4)

__global__ __launch_bounds__(256) void k2_tanh(
    const unsigned short* __restrict__ Yb,
    const float* __restrict__ Wout, const float* __restrict__ bout,
    float* __restrict__ out)
{
    __shared__ float e1s[2][32][LDA2];
    __shared__ float e2s[2][32][LDA2];
    __shared__ float wo[A_];
    __shared__ float wsum_s[4];

    const int t  = threadIdx.x;
    const int jt = blockIdx.x;    // 0..3  (j-tile of 32)
    const int it = blockIdx.y;    // 0..3  (i-tile of 32)
    const int b  = blockIdx.z;

    float wsacc = 0.f;
    for (int k=t; k<A_; k+=256){ float w = Wout[k]; wo[k] = w; wsacc += w; }
#pragma unroll
    for (int off=32; off>=1; off>>=1) wsacc += __shfl_down(wsacc, off, 64);
    if ((t&63)==0) wsum_s[t>>6] = wsacc;

    const unsigned short* yb = Yb + (size_t)b*N_*OC;
    const int sr = t>>4;         // 0..15 (staging row, +16 for second)
    const int sc = (t&15)*8;     // 0..120 elems
    int i2a = it*32 + sr + 1;      if (i2a > 127) i2a = 127;
    int i2b = it*32 + sr + 17;     if (i2b > 127) i2b = 127;

    // chunk-0 loads + write buf0
    {
        uint4 v1a = *(const uint4*)&yb[(size_t)(jt*32 + sr     )*OC + sc];
        uint4 v1b = *(const uint4*)&yb[(size_t)(jt*32 + sr + 16)*OC + sc];
        uint4 v2a = *(const uint4*)&yb[(size_t)i2a*OC + A_ + sc];
        uint4 v2b = *(const uint4*)&yb[(size_t)i2b*OC + A_ + sc];
        uint4 v = v1a;
        *(float4*)&e1s[0][sr][sc]   = float4{bf2f_lo(v.x),bf2f_hi(v.x),bf2f_lo(v.y),bf2f_hi(v.y)};
        *(float4*)&e1s[0][sr][sc+4] = float4{bf2f_lo(v.z),bf2f_hi(v.z),bf2f_lo(v.w),bf2f_hi(v.w)};
        v = v1b;
        *(float4*)&e1s[0][sr+16][sc]   = float4{bf2f_lo(v.x),bf2f_hi(v.x),bf2f_lo(v.y),bf2f_hi(v.y)};
        *(float4*)&e1s[0][sr+16][sc+4] = float4{bf2f_lo(v.z),bf2f_hi(v.z),bf2f_lo(v.w),bf2f_hi(v.w)};
        v = v2a;
        *(float4*)&e2s[0][sr][sc]   = float4{bf2f_lo(v.x),bf2f_hi(v.x),bf2f_lo(v.y),bf2f_hi(v.y)};
        *(float4*)&e2s[0][sr][sc+4] = float4{bf2f_lo(v.z),bf2f_hi(v.z),bf2f_lo(v.w),bf2f_hi(v.w)};
        v = v2b;
        *(float4*)&e2s[0][sr+16][sc]   = float4{bf2f_lo(v.x),bf2f_hi(v.x),bf2f_lo(v.y),bf2f_hi(v.y)};
        *(float4*)&e2s[0][sr+16][sc+4] = float4{bf2f_lo(v.z),bf2f_hi(v.z),bf2f_lo(v.w),bf2f_hi(v.w)};
    }
    __syncthreads();

    const int jl = t&15, il = t>>4;
    float a00=0.f, a01=0.f, a10=0.f, a11=0.f;

#pragma unroll
    for (int ch=0; ch<4; ++ch) {
        const int cur = ch&1;
        uint4 v1a, v1b, v2a, v2b;
        if (ch<3) {                   // early-issue next chunk's loads
            const int a0n = (ch+1)*ACH;
            v1a = *(const uint4*)&yb[(size_t)(jt*32 + sr     )*OC + a0n + sc];
            v1b = *(const uint4*)&yb[(size_t)(jt*32 + sr + 16)*OC + a0n + sc];
            v2a = *(const uint4*)&yb[(size_t)i2a*OC + A_ + a0n + sc];
            v2b = *(const uint4*)&yb[(size_t)i2b*OC + A_ + a0n + sc];
        }
        const int a0 = ch*ACH;
#pragma unroll 4
        for (int c=0; c<ACH; c+=4) {
            float4 u0 = *(const float4*)&e1s[cur][jl     ][c];
            float4 u1 = *(const float4*)&e1s[cur][jl + 16][c];
            float4 v0 = *(const float4*)&e2s[cur][il     ][c];
            float4 v1 = *(const float4*)&e2s[cur][il + 16][c];
            float4 w  = *(const float4*)&wo[a0 + c];
            a00 += w.x * __builtin_amdgcn_rcpf(fmaf(u0.x, v0.x, 1.f));
            a01 += w.x * __builtin_amdgcn_rcpf(fmaf(u1.x, v0.x, 1.f));
            a10 += w.x * __builtin_amdgcn_rcpf(fmaf(u0.x, v1.x, 1.f));
            a11 += w.x * __builtin_amdgcn_rcpf(fmaf(u1.x, v1.x, 1.f));
            a00 += w.y * __builtin_amdgcn_rcpf(fmaf(u0.y, v0.y, 1.f));
            a01 += w.y * __builtin_amdgcn_rcpf(fmaf(u1.y, v0.y, 1.f));
            a10 += w.y * __builtin_amdgcn_rcpf(fmaf(u0.y, v1.y, 1.f));
            a11 += w.y * __builtin_amdgcn_rcpf(fmaf(u1.y, v1.y, 1.f));
            a00 += w.z * __builtin_amdgcn_rcpf(fmaf(u0.z, v0.z, 1.f));
            a01 += w.z * __builtin_amdgcn_rcpf(fmaf(u1.z, v0.z, 1.f));
            a10 += w.z * __builtin_amdgcn_rcpf(fmaf(u0.z, v1.z, 1.f));
            a11 += w.z * __builtin_amdgcn_rcpf(fmaf(u1.z, v1.z, 1.f));
            a00 += w.w * __builtin_amdgcn_rcpf(fmaf(u0.w, v0.w, 1.f));
            a01 += w.w * __builtin_amdgcn_rcpf(fmaf(u1.w, v0.w, 1.f));
            a10 += w.w * __builtin_amdgcn_rcpf(fmaf(u0.w, v1.w, 1.f));
            a11 += w.w * __builtin_amdgcn_rcpf(fmaf(u1.w, v1.w, 1.f));
        }
        if (ch<3) {                   // write-late into the other buffer
            const int nxt = cur^1;
            uint4 v = v1a;
            *(float4*)&e1s[nxt][sr][sc]   = float4{bf2f_lo(v.x),bf2f_hi(v.x),bf2f_lo(v.y),bf2f_hi(v.y)};
            *(float4*)&e1s[nxt][sr][sc+4] = float4{bf2f_lo(v.z),bf2f_hi(v.z),bf2f_lo(v.w),bf2f_hi(v.w)};
            v = v1b;
            *(float4*)&e1s[nxt][sr+16][sc]   = float4{bf2f_lo(v.x),bf2f_hi(v.x),bf2f_lo(v.y),bf2f_hi(v.y)};
            *(float4*)&e1s[nxt][sr+16][sc+4] = float4{bf2f_lo(v.z),bf2f_hi(v.z),bf2f_lo(v.w),bf2f_hi(v.w)};
            v = v2a;
            *(float4*)&e2s[nxt][sr][sc]   = float4{bf2f_lo(v.x),bf2f_hi(v.x),bf2f_lo(v.y),bf2f_hi(v.y)};
            *(float4*)&e2s[nxt][sr][sc+4] = float4{bf2f_lo(v.z),bf2f_hi(v.z),bf2f_lo(v.w),bf2f_hi(v.w)};
            v = v2b;
            *(float4*)&e2s[nxt][sr+16][sc]   = float4{bf2f_lo(v.x),bf2f_hi(v.x),bf2f_lo(v.y),bf2f_hi(v.y)};
            *(float4*)&e2s[nxt][sr+16][sc+4] = float4{bf2f_lo(v.z),bf2f_hi(v.z),bf2f_lo(v.w),bf2f_hi(v.w)};
            __syncthreads();          // buf[nxt] ready; readers of buf[cur] done
        }
    }

    const float wsum = wsum_s[0] + wsum_s[1] + wsum_s[2] + wsum_s[3];
    const float bo   = bout[0];
    const int i0 = it*32 + il;        // x2-row = i0+1
    const int j0 = jt*32 + jl;

    if (i0 < 127) {
        out[((size_t)(b*127) + i0) * 128 + j0     ] = wsum - 2.f*a00 + bo;
        out[((size_t)(b*127) + i0) * 128 + j0 + 16] = wsum - 2.f*a01 + bo;
    }
    if (i0 + 16 < 127) {
        out[((size_t)(b*127) + i0 + 16) * 128 + j0     ] = wsum - 2.f*a10 + bo;
        out[((size_t)(b*127) + i0 + 16) * 128 + j0 + 16] = wsum - 2.f*a11 + bo;
    }
}

extern "C" void kernel_launch(void* const* d_in, const int* in_sizes, int n_in,
                              void* d_out, int out_size, void* d_ws, size_t ws_size,
                              hipStream_t stream) {
    const float* x    = (const float*)d_in[0];
    const float* W1   = (const float*)d_in[1];
    const float* b1   = (const float*)d_in[2];
    const float* W2   = (const float*)d_in[3];
    const float* b2   = (const float*)d_in[4];
    const float* Wout = (const float*)d_in[5];
    const float* bout = (const float*)d_in[6];
    float* out = (float*)d_out;

    char* ws = (char*)d_ws;
    unsigned short* Yb  = (unsigned short*)ws;                              // 8 MB
    unsigned short* Xb  = (unsigned short*)(ws + (8u<<20));                 // 4 MB
    unsigned short* W1b = (unsigned short*)(ws + (12u<<20));                // 512 KB
    unsigned short* W2b = (unsigned short*)(ws + (12u<<20) + (1u<<19));     // 512 KB

    k0_cvt<<<1280, 256, 0, stream>>>(x, W1, W2, Xb, W1b, W2b);

    dim3 g1(R_/64, OC/64);       // (64, 16) = 1024 blocks
    k1_mfma<<<g1, 256, 0, stream>>>(Xb, W1b, b1, W2b, b2, Yb);

    dim3 g2(4, 4, B_);           // (4, 4, 32) = 512 blocks
    k2_tanh<<<g2, 256, 0, stream>>>(Yb, Wout, bout, out);
}

// Round 8
// 114.545 us; speedup vs baseline: 1.0276x; 1.0276x over previous
//
#include <hip/hip_runtime.h>
#include <hip/hip_bf16.h>

#define B_ 32
#define N_ 128
#define D_ 512
#define A_ 512
#define R_ (B_*N_)     // 4096 rows
#define OC 1024        // fused Y cols (E1 | E2)
#define CEXP 2.8853900817779268f   // 2*log2(e)

typedef __attribute__((ext_vector_type(8)))  short frag_ab;   // 8 bf16
typedef __attribute__((ext_vector_type(16))) float frag_c;    // 16 f32 (32x32 acc)

__device__ inline unsigned pack2bf(float a, float b) {
    unsigned ua = __builtin_bit_cast(unsigned, a) + 0x8000u;
    unsigned ub = __builtin_bit_cast(unsigned, b) + 0x8000u;
    return __builtin_amdgcn_perm(ub, ua, 0x07060302);
}
__device__ inline float bf2f_lo(unsigned u){ return __builtin_bit_cast(float, u << 16); }
__device__ inline float bf2f_hi(unsigned u){ return __builtin_bit_cast(float, u & 0xffff0000u); }
__device__ inline void wr8(float* dst, uint4 v) {
    *(float4*)dst     = float4{bf2f_lo(v.x),bf2f_hi(v.x),bf2f_lo(v.y),bf2f_hi(v.y)};
    *(float4*)(dst+4) = float4{bf2f_lo(v.z),bf2f_hi(v.z),bf2f_lo(v.w),bf2f_hi(v.w)};
}

// ---------------- Kernel 0: fp32 -> bf16 conversion of X, W1, W2 ----------
__global__ __launch_bounds__(256) void k0_cvt(
    const float* __restrict__ X, const float* __restrict__ W1,
    const float* __restrict__ W2,
    unsigned short* __restrict__ Xb, unsigned short* __restrict__ W1b,
    unsigned short* __restrict__ W2b)
{
    const int NX = R_*D_/8, NW = A_*D_/8;
    int i = blockIdx.x*256 + threadIdx.x;
    const float* src; unsigned short* dst; int off;
    if (i < NX)            { src = X;  dst = Xb;  off = i; }
    else if (i < NX+NW)    { src = W1; dst = W1b; off = i-NX; }
    else if (i < NX+2*NW)  { src = W2; dst = W2b; off = i-NX-NW; }
    else return;
    float4 a = ((const float4*)src)[off*2];
    float4 c = ((const float4*)src)[off*2+1];
    uint4 o;
    o.x = pack2bf(a.x,a.y); o.y = pack2bf(a.z,a.w);
    o.z = pack2bf(c.x,c.y); o.w = pack2bf(c.z,c.w);
    ((uint4*)dst)[off] = o;
}

// ---------------- Kernel 1: Yb = bf16(exp2(C*(X*[W1;W2]^T + [b1;b2]))) ----
// 128x128 tile, BK=32, 4 waves (2x2), each wave 64x64 via 2x2 of 32x32x16
// MFMA (LDS:MFMA 1:1 balanced). LDK=36: odd-dword-pair stride -> 2-way-free
// bank access, rows 8B-aligned. Double-buffered, write-late staging.
#define LDK1 36

__global__ __launch_bounds__(256) void k1_mfma(
    const unsigned short* __restrict__ Xb,
    const unsigned short* __restrict__ W1b, const float* __restrict__ b1,
    const unsigned short* __restrict__ W2b, const float* __restrict__ b2,
    unsigned short* __restrict__ Yb)
{
    __shared__ unsigned short As[2][128*LDK1];
    __shared__ unsigned short Bs[2][128*LDK1];

    const int t = threadIdx.x, lane = t&63, wid = t>>6;
    const int wr = wid>>1, wc = wid&1;          // wave 64x64 quadrant
    const int row0 = blockIdx.x*128, col0 = blockIdx.y*128;
    const unsigned short* Wb = (col0 < A_) ? W1b : W2b;
    const float* bb = (col0 < A_) ? b1 : b2;
    const int wrow0 = col0 & (A_-1);

    const int srow = t>>1;          // 0..127 (staging row)
    const int scol = (t&1)*16;      // 0 or 16 (elems)

    frag_c acc[2][2];
#pragma unroll
    for (int i=0;i<2;++i)
#pragma unroll
        for (int j=0;j<2;++j)
#pragma unroll
            for (int r=0;r<16;++r) acc[i][j][r] = 0.f;

    const int fr = lane & 31;          // M/N row within 32-tile
    const int ko = (lane >> 5) * 8;    // k-offset 0 or 8

    { // prologue: stage K-chunk 0 into buf0
        const unsigned short* px = &Xb[(size_t)(row0 +srow)*D_ + scol];
        const unsigned short* pw = &Wb[(size_t)(wrow0+srow)*D_ + scol];
        uint4 a0 = *(const uint4*)px, a1 = *(const uint4*)(px+8);
        uint4 b0 = *(const uint4*)pw, b1v = *(const uint4*)(pw+8);
        *(uint4*)&As[0][srow*LDK1 + scol]     = a0;
        *(uint4*)&As[0][srow*LDK1 + scol + 8] = a1;
        *(uint4*)&Bs[0][srow*LDK1 + scol]     = b0;
        *(uint4*)&Bs[0][srow*LDK1 + scol + 8] = b1v;
    }
    __syncthreads();

#pragma unroll
    for (int s = 0; s < 16; ++s) {
        const int cur = s & 1;
        uint4 a0, a1, b0, b1v;
        if (s < 15) {   // early-issue next K-chunk's loads
            const int k0 = (s+1)*32;
            const unsigned short* px = &Xb[(size_t)(row0 +srow)*D_ + k0 + scol];
            const unsigned short* pw = &Wb[(size_t)(wrow0+srow)*D_ + k0 + scol];
            a0 = *(const uint4*)px; a1 = *(const uint4*)(px+8);
            b0 = *(const uint4*)pw; b1v = *(const uint4*)(pw+8);
        }
        frag_ab af[2][2], bf[2][2];
#pragma unroll
        for (int mt=0; mt<2; ++mt)
#pragma unroll
            for (int ks=0; ks<2; ++ks) {
                af[mt][ks] = *(const frag_ab*)&As[cur][(wr*64+mt*32+fr)*LDK1 + ks*16 + ko];
                bf[mt][ks] = *(const frag_ab*)&Bs[cur][(wc*64+mt*32+fr)*LDK1 + ks*16 + ko];
            }
#pragma unroll
        for (int ks=0; ks<2; ++ks)
#pragma unroll
            for (int mt=0; mt<2; ++mt)
#pragma unroll
                for (int nt=0; nt<2; ++nt)
                    acc[mt][nt] = __builtin_amdgcn_mfma_f32_32x32x16_bf16(
                        af[mt][ks], bf[nt][ks], acc[mt][nt], 0, 0, 0);
        if (s < 15) {   // write-late into the other buffer
            *(uint4*)&As[cur^1][srow*LDK1 + scol]     = a0;
            *(uint4*)&As[cur^1][srow*LDK1 + scol + 8] = a1;
            *(uint4*)&Bs[cur^1][srow*LDK1 + scol]     = b0;
            *(uint4*)&Bs[cur^1][srow*LDK1 + scol + 8] = b1v;
        }
        __syncthreads();
    }

    // epilogue: 32x32 C/D layout col=lane&31, row=(reg&3)+8*(reg>>2)+4*(lane>>5)
#pragma unroll
    for (int mt=0; mt<2; ++mt) {
        const int rbase = row0 + wr*64 + mt*32 + 4*(lane>>5);
#pragma unroll
        for (int nt=0; nt<2; ++nt) {
            const int cc = col0 + wc*64 + nt*32 + (lane&31);
            const float bias = bb[cc & (A_-1)];
#pragma unroll
            for (int r=0; r<16; ++r) {
                const int rr = rbase + (r&3) + 8*(r>>2);
                float e = __builtin_amdgcn_exp2f(CEXP*(acc[mt][nt][r] + bias));
                Yb[(size_t)rr*OC + cc] =
                    (unsigned short)((__builtin_bit_cast(unsigned, e) + 0x8000u) >> 16);
            }
        }
    }
}

// ---------------- Kernel 2 ----------------
// out[b,i,j] += wsum_half - 2*sum_{a in half} wo[a]/(1+E1[j,a]*E2[i+1,a]) (+bout)
// a-split x2 (atomicAdd into zeroed out) -> grid 1024 = 4 blk/CU, 16 waves/CU.
// Reciprocal pairing: w0/r + w1/s = (w0*s+w1*r)*rcp(r*s) halves rcp count.
#define ACH2 128
#define LD2 (ACH2+4)

__global__ __launch_bounds__(256) void k2_tanh(
    const unsigned short* __restrict__ Yb,
    const float* __restrict__ Wout, const float* __restrict__ bout,
    float* __restrict__ out)
{
    __shared__ float e1s[32][LD2];
    __shared__ float e2s[32][LD2];
    __shared__ float wo[256];
    __shared__ float wsum_s[4];

    const int t  = threadIdx.x;
    const int jt = blockIdx.x, it = blockIdx.y;
    const int b  = blockIdx.z >> 1, ah = blockIdx.z & 1;
    const int abase = ah << 8;

    {
        float w = Wout[abase + t];
        wo[t] = w;
#pragma unroll
        for (int off=32; off>=1; off>>=1) w += __shfl_down(w, off, 64);
        if ((t&63)==0) wsum_s[t>>6] = w;
    }

    const unsigned short* yb = Yb + (size_t)b*N_*OC;
    const int sr = t>>4, sc = (t&15)*8;
    int i2a = it*32 + sr + 1;  if (i2a > 127) i2a = 127;
    int i2b = it*32 + sr + 17; if (i2b > 127) i2b = 127;
    const size_t o1a = (size_t)(jt*32+sr   )*OC + abase + sc;
    const size_t o1b = (size_t)(jt*32+sr+16)*OC + abase + sc;
    const size_t o2a = (size_t)i2a*OC + A_ + abase + sc;
    const size_t o2b = (size_t)i2b*OC + A_ + abase + sc;

    {   // stage chunk 0
        uint4 v1a = *(const uint4*)&yb[o1a];
        uint4 v1b = *(const uint4*)&yb[o1b];
        uint4 v2a = *(const uint4*)&yb[o2a];
        uint4 v2b = *(const uint4*)&yb[o2b];
        wr8(&e1s[sr][sc], v1a); wr8(&e1s[sr+16][sc], v1b);
        wr8(&e2s[sr][sc], v2a); wr8(&e2s[sr+16][sc], v2b);
    }
    __syncthreads();

    // prefetch chunk 1 (lands under chunk-0 compute)
    uint4 n1a = *(const uint4*)&yb[o1a + ACH2];
    uint4 n1b = *(const uint4*)&yb[o1b + ACH2];
    uint4 n2a = *(const uint4*)&yb[o2a + ACH2];
    uint4 n2b = *(const uint4*)&yb[o2b + ACH2];

    const int jl = t&15, il = t>>4;
    float a00=0.f, a01=0.f, a10=0.f, a11=0.f;

#pragma unroll 4
    for (int c=0; c<ACH2; c+=2) {
        float2 u0 = *(const float2*)&e1s[jl   ][c];
        float2 u1 = *(const float2*)&e1s[jl+16][c];
        float2 v0 = *(const float2*)&e2s[il   ][c];
        float2 v1 = *(const float2*)&e2s[il+16][c];
        float2 w  = *(const float2*)&wo[c];
        { float r=fmaf(u0.x,v0.x,1.f), s=fmaf(u0.y,v0.y,1.f);
          a00 = fmaf(fmaf(w.x,s,w.y*r), __builtin_amdgcn_rcpf(r*s), a00); }
        { float r=fmaf(u1.x,v0.x,1.f), s=fmaf(u1.y,v0.y,1.f);
          a01 = fmaf(fmaf(w.x,s,w.y*r), __builtin_amdgcn_rcpf(r*s), a01); }
        { float r=fmaf(u0.x,v1.x,1.f), s=fmaf(u0.y,v1.y,1.f);
          a10 = fmaf(fmaf(w.x,s,w.y*r), __builtin_amdgcn_rcpf(r*s), a10); }
        { float r=fmaf(u1.x,v1.x,1.f), s=fmaf(u1.y,v1.y,1.f);
          a11 = fmaf(fmaf(w.x,s,w.y*r), __builtin_amdgcn_rcpf(r*s), a11); }
    }
    __syncthreads();
    wr8(&e1s[sr][sc], n1a); wr8(&e1s[sr+16][sc], n1b);
    wr8(&e2s[sr][sc], n2a); wr8(&e2s[sr+16][sc], n2b);
    __syncthreads();

#pragma unroll 4
    for (int c=0; c<ACH2; c+=2) {
        float2 u0 = *(const float2*)&e1s[jl   ][c];
        float2 u1 = *(const float2*)&e1s[jl+16][c];
        float2 v0 = *(const float2*)&e2s[il   ][c];
        float2 v1 = *(const float2*)&e2s[il+16][c];
        float2 w  = *(const float2*)&wo[ACH2 + c];
        { float r=fmaf(u0.x,v0.x,1.f), s=fmaf(u0.y,v0.y,1.f);
          a00 = fmaf(fmaf(w.x,s,w.y*r), __builtin_amdgcn_rcpf(r*s), a00); }
        { float r=fmaf(u1.x,v0.x,1.f), s=fmaf(u1.y,v0.y,1.f);
          a01 = fmaf(fmaf(w.x,s,w.y*r), __builtin_amdgcn_rcpf(r*s), a01); }
        { float r=fmaf(u0.x,v1.x,1.f), s=fmaf(u0.y,v1.y,1.f);
          a10 = fmaf(fmaf(w.x,s,w.y*r), __builtin_amdgcn_rcpf(r*s), a10); }
        { float r=fmaf(u1.x,v1.x,1.f), s=fmaf(u1.y,v1.y,1.f);
          a11 = fmaf(fmaf(w.x,s,w.y*r), __builtin_amdgcn_rcpf(r*s), a11); }
    }

    const float wsum = wsum_s[0]+wsum_s[1]+wsum_s[2]+wsum_s[3];
    const float base = wsum + (ah ? 0.f : bout[0]);
    const int i0 = it*32 + il, j0 = jt*32 + jl;
    float* ob = out + (size_t)b*127*128;
    if (i0 < 127) {
        atomicAdd(&ob[i0*128 + j0     ], base - 2.f*a00);
        atomicAdd(&ob[i0*128 + j0 + 16], base - 2.f*a01);
    }
    if (i0 + 16 < 127) {
        atomicAdd(&ob[(i0+16)*128 + j0     ], base - 2.f*a10);
        atomicAdd(&ob[(i0+16)*128 + j0 + 16], base - 2.f*a11);
    }
}

extern "C" void kernel_launch(void* const* d_in, const int* in_sizes, int n_in,
                              void* d_out, int out_size, void* d_ws, size_t ws_size,
                              hipStream_t stream) {
    const float* x    = (const float*)d_in[0];
    const float* W1   = (const float*)d_in[1];
    const float* b1   = (const float*)d_in[2];
    const float* W2   = (const float*)d_in[3];
    const float* b2   = (const float*)d_in[4];
    const float* Wout = (const float*)d_in[5];
    const float* bout = (const float*)d_in[6];
    float* out = (float*)d_out;

    char* ws = (char*)d_ws;
    unsigned short* Yb  = (unsigned short*)ws;                              // 8 MB
    unsigned short* Xb  = (unsigned short*)(ws + (8u<<20));                 // 4 MB
    unsigned short* W1b = (unsigned short*)(ws + (12u<<20));                // 512 KB
    unsigned short* W2b = (unsigned short*)(ws + (12u<<20) + (1u<<19));     // 512 KB

    k0_cvt<<<1280, 256, 0, stream>>>(x, W1, W2, Xb, W1b, W2b);

    dim3 g1(R_/128, OC/128);     // (32, 8) = 256 blocks
    k1_mfma<<<g1, 256, 0, stream>>>(Xb, W1b, b1, W2b, b2, Yb);

    hipMemsetAsync(d_out, 0, (size_t)out_size*sizeof(float), stream);

    dim3 g2(4, 4, 2*B_);         // (4, 4, 64) = 1024 blocks, a-split x2
    k2_tanh<<<g2, 256, 0, stream>>>(Yb, Wout, bout, out);
}